// Round 3
// baseline (671.635 us; speedup 1.0000x reference)
//
#include <hip/hip_runtime.h>
#include <hip/hip_bf16.h>
#include <stdint.h>

namespace {
constexpr int kB = 4, kT = 2048, kC = 1024, kH = 16, kD = 64;
constexpr int kM = kB * kT;        // 8192
constexpr int kR = 8;
constexpr float kScaling = 4.0f;   // ALPHA / R
constexpr float kInvSqrtD = 0.125f;
}

typedef short short8 __attribute__((ext_vector_type(8)));
typedef float f32x4 __attribute__((ext_vector_type(4)));
typedef unsigned short ushort4v __attribute__((ext_vector_type(4)));
typedef unsigned short ushort8v __attribute__((ext_vector_type(8)));

// ---------------------------------------------------------------------------
// fp32 -> bf16 (RNE) bit helpers; split x = hi + lo, both bf16.
// ---------------------------------------------------------------------------
__device__ inline uint32_t f32_to_bf16_rne(float f) {
  uint32_t u = __float_as_uint(f);
  return (u + 0x7fffu + ((u >> 16) & 1u)) >> 16;
}

__device__ inline void split4(const float4 v, ushort4v& h, ushort4v& l) {
  const float f[4] = {v.x, v.y, v.z, v.w};
#pragma unroll
  for (int j = 0; j < 4; ++j) {
    const uint32_t hb = f32_to_bf16_rne(f[j]);
    const float hf = __uint_as_float(hb << 16);
    const uint32_t lb = f32_to_bf16_rne(f[j] - hf);
    h[j] = (unsigned short)hb;
    l[j] = (unsigned short)lb;
  }
}

// ---------------------------------------------------------------------------
// Kernel 1: XA[m][0..7] = x[m]·Aq[r][:],  XA[m][8..15] = x[m]·Av[r][:]
// ---------------------------------------------------------------------------
__global__ __launch_bounds__(256) void lora_xa_kernel(
    const float* __restrict__ x, const float* __restrict__ Aq,
    const float* __restrict__ Av, float* __restrict__ xa) {
  const int wave = threadIdx.x >> 6;
  const int lane = threadIdx.x & 63;
  const int row = (blockIdx.x << 2) + wave;
  const float4* xr = reinterpret_cast<const float4*>(x) + (size_t)row * (kC / 4);
  const float4* aq = reinterpret_cast<const float4*>(Aq);
  const float4* av = reinterpret_cast<const float4*>(Av);
  float acc[16];
#pragma unroll
  for (int r = 0; r < 16; ++r) acc[r] = 0.f;
#pragma unroll
  for (int jj = 0; jj < (kC / 4) / 64; ++jj) {
    const int j = lane + jj * 64;
    const float4 xv = xr[j];
#pragma unroll
    for (int r = 0; r < 8; ++r) {
      const float4 a = aq[r * (kC / 4) + j];
      acc[r] += xv.x * a.x + xv.y * a.y + xv.z * a.z + xv.w * a.w;
      const float4 b = av[r * (kC / 4) + j];
      acc[8 + r] += xv.x * b.x + xv.y * b.y + xv.z * b.z + xv.w * b.w;
    }
  }
#pragma unroll
  for (int r = 0; r < 16; ++r) {
    float v = acc[r];
#pragma unroll
    for (int off = 32; off > 0; off >>= 1) v += __shfl_xor(v, off, 64);
    if (lane == 0) xa[(size_t)row * 16 + r] = v;
  }
}

// ---------------------------------------------------------------------------
// Kernel 2: bf16x3 MFMA GEMM  out[m][n] = sum_k X[m][k]*W[n][k] + bias[n]
// 128x128 tile, BK=32, 4 waves (2x2 of 64x64), 16x16x32 bf16 MFMA.
// MFMA layouts (m89-verified): A: row=lane&15, k=8*(lane>>4)+j
//                              B: col=lane&15, same k
//                              D: col=lane&15, row=4*(lane>>4)+i
// ---------------------------------------------------------------------------
__global__ __launch_bounds__(256, 2) void gemm_bf16x3_kernel(
    const float* __restrict__ X, const float* __restrict__ W,
    const float* __restrict__ bias, const float* __restrict__ xa,
    const float* __restrict__ Bm, float* __restrict__ out,
    const int lora_sel /* -1 none, 0 q-cols, 8 v-cols of xa */,
    const int out_bhtd) {
  constexpr int BK = 32;
  constexpr int LDP = 40;  // padded LDS row stride in shorts
  __shared__ unsigned short Ah[128 * LDP];
  __shared__ unsigned short Al[128 * LDP];
  __shared__ unsigned short Bh[128 * LDP];
  __shared__ unsigned short Bl[128 * LDP];

  const int tid = threadIdx.x;
  const int m0 = blockIdx.y << 7;
  const int n0 = blockIdx.x << 7;
  const int wave = tid >> 6, lane = tid & 63;
  const int wr = wave >> 1, wc = wave & 1;
  const int lrow = lane & 15;
  const int lkg = lane >> 4;

  const int r0 = tid >> 3;            // 0..31 -> rows r0+32i
  const int c4 = (tid & 7) << 2;      // k offset 0..28
  const float* xbase = X + (size_t)(m0 + r0) * kC + c4;
  const float* wbase = W + (size_t)(n0 + r0) * kC + c4;

  f32x4 acc[4][4];
#pragma unroll
  for (int a = 0; a < 4; ++a)
#pragma unroll
    for (int b = 0; b < 4; ++b) acc[a][b] = (f32x4){0.f, 0.f, 0.f, 0.f};

  float4 ga[4], gb[4];
#pragma unroll
  for (int i = 0; i < 4; ++i) {
    ga[i] = *reinterpret_cast<const float4*>(xbase + (size_t)i * 32 * kC);
    gb[i] = *reinterpret_cast<const float4*>(wbase + (size_t)i * 32 * kC);
  }

  for (int k0 = 0; k0 < kC; k0 += BK) {
#pragma unroll
    for (int i = 0; i < 4; ++i) {
      const int ro = (r0 + 32 * i) * LDP + c4;
      ushort4v ha, la2, hb, lb;
      split4(ga[i], ha, la2);
      split4(gb[i], hb, lb);
      *reinterpret_cast<ushort4v*>(&Ah[ro]) = ha;
      *reinterpret_cast<ushort4v*>(&Al[ro]) = la2;
      *reinterpret_cast<ushort4v*>(&Bh[ro]) = hb;
      *reinterpret_cast<ushort4v*>(&Bl[ro]) = lb;
    }
    __syncthreads();

    if (k0 + BK < kC) {
#pragma unroll
      for (int i = 0; i < 4; ++i) {
        ga[i] = *reinterpret_cast<const float4*>(xbase + (k0 + BK) + (size_t)i * 32 * kC);
        gb[i] = *reinterpret_cast<const float4*>(wbase + (k0 + BK) + (size_t)i * 32 * kC);
      }
    }

    short8 ah[4], al[4];
#pragma unroll
    for (int rb = 0; rb < 4; ++rb) {
      const int off = (wr * 64 + rb * 16 + lrow) * LDP + lkg * 8;
      ah[rb] = *reinterpret_cast<const short8*>(&Ah[off]);
      al[rb] = *reinterpret_cast<const short8*>(&Al[off]);
    }
#pragma unroll
    for (int cb = 0; cb < 4; ++cb) {
      const int off = (wc * 64 + cb * 16 + lrow) * LDP + lkg * 8;
      const short8 bhf = *reinterpret_cast<const short8*>(&Bh[off]);
      const short8 blf = *reinterpret_cast<const short8*>(&Bl[off]);
#pragma unroll
      for (int rb = 0; rb < 4; ++rb) {
        acc[rb][cb] = __builtin_amdgcn_mfma_f32_16x16x32_bf16(ah[rb], bhf, acc[rb][cb], 0, 0, 0);
        acc[rb][cb] = __builtin_amdgcn_mfma_f32_16x16x32_bf16(ah[rb], blf, acc[rb][cb], 0, 0, 0);
        acc[rb][cb] = __builtin_amdgcn_mfma_f32_16x16x32_bf16(al[rb], bhf, acc[rb][cb], 0, 0, 0);
      }
    }
    __syncthreads();
  }

#pragma unroll
  for (int rb = 0; rb < 4; ++rb) {
#pragma unroll
    for (int i = 0; i < 4; ++i) {
      const int m = m0 + wr * 64 + rb * 16 + (lkg << 2) + i;
      float la[kR];
      if (lora_sel >= 0) {
#pragma unroll
        for (int r = 0; r < kR; ++r) la[r] = xa[(size_t)m * 16 + lora_sel + r];
      }
#pragma unroll
      for (int cb = 0; cb < 4; ++cb) {
        const int n = n0 + wc * 64 + cb * 16 + lrow;
        float v = acc[rb][cb][i] + bias[n];
        if (lora_sel >= 0) {
          float lv = 0.f;
#pragma unroll
          for (int r = 0; r < kR; ++r)
            lv = fmaf(la[r], Bm[(size_t)n * kR + r], lv);
          v += kScaling * lv;
        }
        if (out_bhtd) {
          const int bb_ = m >> 11;
          const int t = m & (kT - 1);
          const int h = n >> 6;
          const int dd = n & (kD - 1);
          out[(((size_t)bb_ * kH + h) * kT + t) * kD + dd] = v;
        } else {
          out[(size_t)m * kC + n] = v;
        }
      }
    }
  }
}

// ---------------------------------------------------------------------------
// Kernel 3: flash attention, bf16 MFMA.
//   Block = 256 thr (4 waves), 64 q-rows (16/wave), KV tiles of 64.
//   Swapped QK^T: S-frag = mfma(A=K, B=Q) -> D col=q(lane&15), row=kv.
//   QK^T in bf16x3 (Q scaled by 1/8 at staging); P,V plain bf16
//   (diffuse softmax -> rounding noise averages out).
//   PV: O^T-frag = mfma(A=Vt, B=P) -> D col=q, row=d.
//   LDS: 4 planes of 64x72 shorts (Q planes alias K planes) = 36.8 KB.
// ---------------------------------------------------------------------------
__global__ __launch_bounds__(256, 3) void attn_mfma_kernel(
    const float* __restrict__ q, const float* __restrict__ k,
    const float* __restrict__ v, float* __restrict__ ctx) {
  constexpr int LDP = 72;
  __shared__ unsigned short P0[64 * LDP];  // Qh then Kh
  __shared__ unsigned short P1[64 * LDP];  // Ql then Kl
  __shared__ unsigned short P2[64 * LDP];  // Vt (hi), rows=d, cols=kv
  __shared__ unsigned short P3[64 * LDP];  // P (bf16), rows=q, cols=kv

  const int tid = threadIdx.x;
  const int wave = tid >> 6, lane = tid & 63;
  const int lrow = lane & 15, lg = lane >> 4;
  const int bh = blockIdx.y;
  const int q0 = blockIdx.x << 6;
  const int b = bh >> 4, h = bh & 15;
  const float* qp = q + (size_t)bh * kT * kD;
  const float* kp = k + (size_t)bh * kT * kD;
  const float* vp = v + (size_t)bh * kT * kD;

  // Staging coords: 16 rows x 4 col-threads; cols (tid&3)*4 + 16u.
  const int sr = tid >> 2;           // 0..63
  const int scb = (tid & 3) << 2;    // 0,4,8,12

  // ---- Stage Q (scaled), hi/lo split.
#pragma unroll
  for (int u = 0; u < 4; ++u) {
    const int c = scb + 16 * u;
    float4 t4 = *reinterpret_cast<const float4*>(qp + (size_t)(q0 + sr) * kD + c);
    t4.x *= kInvSqrtD; t4.y *= kInvSqrtD; t4.z *= kInvSqrtD; t4.w *= kInvSqrtD;
    ushort4v hh, ll;
    split4(t4, hh, ll);
    *reinterpret_cast<ushort4v*>(&P0[sr * LDP + c]) = hh;
    *reinterpret_cast<ushort4v*>(&P1[sr * LDP + c]) = ll;
  }
  __syncthreads();

  // ---- Hoist Q fragments (B-operand: col=q=lrow, k=d=32*ds+8*lg+j).
  short8 qh[2], ql[2];
#pragma unroll
  for (int ds0 = 0; ds0 < 2; ++ds0) {
    const int off = (wave * 16 + lrow) * LDP + ds0 * 32 + lg * 8;
    qh[ds0] = *reinterpret_cast<const short8*>(&P0[off]);
    ql[ds0] = *reinterpret_cast<const short8*>(&P1[off]);
  }
  __syncthreads();  // Q planes now free for K staging.

  f32x4 acc_o[4];
#pragma unroll
  for (int i = 0; i < 4; ++i) acc_o[i] = (f32x4){0.f, 0.f, 0.f, 0.f};
  float m_i = -3.0e38f, l_i = 0.f;

  for (int kt = 0; kt < kT / 64; ++kt) {
    const int k0 = kt << 6;
    // ---- Stage K (hi/lo), coalesced float4 reads.
#pragma unroll
    for (int u = 0; u < 4; ++u) {
      const int c = scb + 16 * u;
      const float4 t4 = *reinterpret_cast<const float4*>(kp + (size_t)(k0 + sr) * kD + c);
      ushort4v hh, ll;
      split4(t4, hh, ll);
      *reinterpret_cast<ushort4v*>(&P0[sr * LDP + c]) = hh;
      *reinterpret_cast<ushort4v*>(&P1[sr * LDP + c]) = ll;
    }
    // ---- Stage V transposed: thread owns column d=tid&63, kv block wave*16.
    {
      const int vd = tid & 63;
      const int vk = wave << 4;
      unsigned short vbuf[16];
#pragma unroll
      for (int i = 0; i < 16; ++i)
        vbuf[i] = (unsigned short)f32_to_bf16_rne(vp[(size_t)(k0 + vk + i) * kD + vd]);
      ushort8v w0, w1;
#pragma unroll
      for (int i = 0; i < 8; ++i) { w0[i] = vbuf[i]; w1[i] = vbuf[8 + i]; }
      *reinterpret_cast<ushort8v*>(&P2[vd * LDP + vk]) = w0;
      *reinterpret_cast<ushort8v*>(&P2[vd * LDP + vk + 8]) = w1;
    }
    __syncthreads();

    // ---- S = K·Q^T (x3). acc_s[kvr]: D row=kv&15, col=q=lrow.
    f32x4 acc_s[4];
#pragma unroll
    for (int kvr = 0; kvr < 4; ++kvr) acc_s[kvr] = (f32x4){0.f, 0.f, 0.f, 0.f};
#pragma unroll
    for (int kvr = 0; kvr < 4; ++kvr) {
#pragma unroll
      for (int ds0 = 0; ds0 < 2; ++ds0) {
        const int off = (kvr * 16 + lrow) * LDP + ds0 * 32 + lg * 8;
        const short8 khf = *reinterpret_cast<const short8*>(&P0[off]);
        const short8 klf = *reinterpret_cast<const short8*>(&P1[off]);
        acc_s[kvr] = __builtin_amdgcn_mfma_f32_16x16x32_bf16(khf, qh[ds0], acc_s[kvr], 0, 0, 0);
        acc_s[kvr] = __builtin_amdgcn_mfma_f32_16x16x32_bf16(khf, ql[ds0], acc_s[kvr], 0, 0, 0);
        acc_s[kvr] = __builtin_amdgcn_mfma_f32_16x16x32_bf16(klf, qh[ds0], acc_s[kvr], 0, 0, 0);
      }
    }

    // ---- Online softmax for q=lrow. Lane holds kv = 16*kvr + 4*lg + i.
    float mx = acc_s[0][0];
#pragma unroll
    for (int kvr = 0; kvr < 4; ++kvr)
#pragma unroll
      for (int i = 0; i < 4; ++i) mx = fmaxf(mx, acc_s[kvr][i]);
    mx = fmaxf(mx, __shfl_xor(mx, 16, 64));
    mx = fmaxf(mx, __shfl_xor(mx, 32, 64));
    const float mnew = fmaxf(m_i, mx);
    const float alpha = __expf(m_i - mnew);
    float rs = 0.f;
    float p[4][4];
#pragma unroll
    for (int kvr = 0; kvr < 4; ++kvr)
#pragma unroll
      for (int i = 0; i < 4; ++i) {
        p[kvr][i] = __expf(acc_s[kvr][i] - mnew);
        rs += p[kvr][i];
      }
    rs += __shfl_xor(rs, 16, 64);
    rs += __shfl_xor(rs, 32, 64);
    l_i = l_i * alpha + rs;
    m_i = mnew;
#pragma unroll
    for (int dr = 0; dr < 4; ++dr)
#pragma unroll
      for (int i = 0; i < 4; ++i) acc_o[dr][i] *= alpha;

    // ---- P -> bf16 -> per-wave LDS strip (within-wave, in-order LDS pipe).
#pragma unroll
    for (int kvr = 0; kvr < 4; ++kvr) {
      ushort4v pu;
#pragma unroll
      for (int i = 0; i < 4; ++i) pu[i] = (unsigned short)f32_to_bf16_rne(p[kvr][i]);
      *reinterpret_cast<ushort4v*>(&P3[(wave * 16 + lrow) * LDP + kvr * 16 + lg * 4]) = pu;
    }
    __builtin_amdgcn_sched_barrier(0);  // keep PV reads after P writes

    // ---- O^T += Vt·P^T : acc_o[dr]: D row=d&15, col=q=lrow.
#pragma unroll
    for (int ks = 0; ks < 2; ++ks) {
      const short8 pf = *reinterpret_cast<const short8*>(
          &P3[(wave * 16 + lrow) * LDP + ks * 32 + lg * 8]);
#pragma unroll
      for (int dr = 0; dr < 4; ++dr) {
        const short8 vf = *reinterpret_cast<const short8*>(
            &P2[(dr * 16 + lrow) * LDP + ks * 32 + lg * 8]);
        acc_o[dr] = __builtin_amdgcn_mfma_f32_16x16x32_bf16(vf, pf, acc_o[dr], 0, 0, 0);
      }
    }
    __syncthreads();
  }

  // ---- Epilogue: O[q][d] = acc_o/l_i -> ctx [B,T,C], C = h*64 + d.
  const float inv = 1.0f / l_i;
  const int qq = q0 + wave * 16 + lrow;
  float* op = ctx + ((size_t)b * kT + qq) * kC + (h << 6);
#pragma unroll
  for (int dr = 0; dr < 4; ++dr) {
    const float4 o4 = make_float4(acc_o[dr][0] * inv, acc_o[dr][1] * inv,
                                  acc_o[dr][2] * inv, acc_o[dr][3] * inv);
    *reinterpret_cast<float4*>(op + dr * 16 + lg * 4) = o4;
  }
}

// ---------------------------------------------------------------------------
extern "C" void kernel_launch(void* const* d_in, const int* in_sizes, int n_in,
                              void* d_out, int out_size, void* d_ws, size_t ws_size,
                              hipStream_t stream) {
  const float* x  = (const float*)d_in[0];
  const float* Wq = (const float*)d_in[1];
  const float* bq = (const float*)d_in[2];
  const float* Wk = (const float*)d_in[3];
  const float* bk = (const float*)d_in[4];
  const float* Wv = (const float*)d_in[5];
  const float* bv = (const float*)d_in[6];
  const float* Wo = (const float*)d_in[7];
  const float* bo = (const float*)d_in[8];
  const float* Aq = (const float*)d_in[9];
  const float* Bq = (const float*)d_in[10];
  const float* Av = (const float*)d_in[11];
  const float* Bv = (const float*)d_in[12];
  float* out = (float*)d_out;

  float* ws = (float*)d_ws;
  float* qb  = ws;                              // [B,H,T,D]
  float* kb  = qb  + (size_t)kM * kC;           // [B,H,T,D]
  float* vb  = kb  + (size_t)kM * kC;           // [B,H,T,D]
  float* ctx = vb  + (size_t)kM * kC;           // [B,T,C]
  float* xa  = ctx + (size_t)kM * kC;           // [M,16]

  hipLaunchKernelGGL(lora_xa_kernel, dim3(kM / 4), dim3(256), 0, stream,
                     x, Aq, Av, xa);

  const dim3 gg(kC / 128, kM / 128);
  hipLaunchKernelGGL(gemm_bf16x3_kernel, gg, dim3(256), 0, stream,
                     x, Wq, bq, xa, Bq, qb, 0, 1);
  hipLaunchKernelGGL(gemm_bf16x3_kernel, gg, dim3(256), 0, stream,
                     x, Wk, bk, nullptr, nullptr, kb, -1, 1);
  hipLaunchKernelGGL(gemm_bf16x3_kernel, gg, dim3(256), 0, stream,
                     x, Wv, bv, xa, Bv, vb, 8, 1);

  hipLaunchKernelGGL(attn_mfma_kernel, dim3(kT / 64, kB * kH), dim3(256), 0, stream,
                     qb, kb, vb, ctx);

  hipLaunchKernelGGL(gemm_bf16x3_kernel, gg, dim3(256), 0, stream,
                     ctx, Wo, bo, nullptr, nullptr, out, -1, 0);
}

// Round 5
// 641.087 us; speedup vs baseline: 1.0476x; 1.0476x over previous
//
#include <hip/hip_runtime.h>
#include <hip/hip_bf16.h>
#include <stdint.h>

namespace {
constexpr int kB = 4, kT = 2048, kC = 1024, kH = 16, kD = 64;
constexpr int kM = kB * kT;        // 8192
constexpr int kR = 8;
constexpr float kScaling = 4.0f;   // ALPHA / R
constexpr float kInvSqrtD = 0.125f;
}

typedef short short8 __attribute__((ext_vector_type(8)));
typedef float f32x4 __attribute__((ext_vector_type(4)));
typedef unsigned short ushort4v __attribute__((ext_vector_type(4)));
typedef unsigned short ushort8v __attribute__((ext_vector_type(8)));

// ---------------------------------------------------------------------------
// fp32 -> bf16 (RNE) bit helpers; split x = hi + lo, both bf16.
// ---------------------------------------------------------------------------
__device__ inline uint32_t f32_to_bf16_rne(float f) {
  uint32_t u = __float_as_uint(f);
  return (u + 0x7fffu + ((u >> 16) & 1u)) >> 16;
}

__device__ inline void split4(const float4 v, ushort4v& h, ushort4v& l) {
  const float f[4] = {v.x, v.y, v.z, v.w};
#pragma unroll
  for (int j = 0; j < 4; ++j) {
    const uint32_t hb = f32_to_bf16_rne(f[j]);
    const float hf = __uint_as_float(hb << 16);
    const uint32_t lb = f32_to_bf16_rne(f[j] - hf);
    h[j] = (unsigned short)hb;
    l[j] = (unsigned short)lb;
  }
}

__device__ inline short8 pack8(ushort4v a, ushort4v b) {
  short8 r;
  r[0] = (short)a[0]; r[1] = (short)a[1]; r[2] = (short)a[2]; r[3] = (short)a[3];
  r[4] = (short)b[0]; r[5] = (short)b[1]; r[6] = (short)b[2]; r[7] = (short)b[3];
  return r;
}

// ---------------------------------------------------------------------------
// Kernel 1: XA[m][0..7] = x[m]·Aq[r][:],  XA[m][8..15] = x[m]·Av[r][:]
// ---------------------------------------------------------------------------
__global__ __launch_bounds__(256) void lora_xa_kernel(
    const float* __restrict__ x, const float* __restrict__ Aq,
    const float* __restrict__ Av, float* __restrict__ xa) {
  const int wave = threadIdx.x >> 6;
  const int lane = threadIdx.x & 63;
  const int row = (blockIdx.x << 2) + wave;
  const float4* xr = reinterpret_cast<const float4*>(x) + (size_t)row * (kC / 4);
  const float4* aq = reinterpret_cast<const float4*>(Aq);
  const float4* av = reinterpret_cast<const float4*>(Av);
  float acc[16];
#pragma unroll
  for (int r = 0; r < 16; ++r) acc[r] = 0.f;
#pragma unroll
  for (int jj = 0; jj < (kC / 4) / 64; ++jj) {
    const int j = lane + jj * 64;
    const float4 xv = xr[j];
#pragma unroll
    for (int r = 0; r < 8; ++r) {
      const float4 a = aq[r * (kC / 4) + j];
      acc[r] += xv.x * a.x + xv.y * a.y + xv.z * a.z + xv.w * a.w;
      const float4 b = av[r * (kC / 4) + j];
      acc[8 + r] += xv.x * b.x + xv.y * b.y + xv.z * b.z + xv.w * b.w;
    }
  }
#pragma unroll
  for (int r = 0; r < 16; ++r) {
    float v = acc[r];
#pragma unroll
    for (int off = 32; off > 0; off >>= 1) v += __shfl_xor(v, off, 64);
    if (lane == 0) xa[(size_t)row * 16 + r] = v;
  }
}

// ---------------------------------------------------------------------------
// Kernel 2: bf16x3 MFMA GEMM  out[m][n] = sum_k X[m][k]*W[n][k] + bias[n]
// 128x128 tile, BK=32, 4 waves (2x2 of 64x64), 16x16x32 bf16 MFMA.
// LDS: packed rows of 128B = chunks 0-3 hi / 4-7 lo, chunk XOR-swizzled by
// (row&7) -> bank-uniform ds_read_b128 / ds_write_b64 (T2).
// out_mode: 0 = fp32 [M][C]; 1 = fp32 [B,H,T,D]; 2 = fp32 V-transposed
//           [B,H,D,T].
// ---------------------------------------------------------------------------
__global__ __launch_bounds__(256, 2) void gemm_bf16x3_kernel(
    const float* __restrict__ X, const float* __restrict__ W,
    const float* __restrict__ bias, const float* __restrict__ xa,
    const float* __restrict__ Bm, float* __restrict__ out,
    const int lora_sel /* -1 none, 0 q-cols, 8 v-cols of xa */,
    const int out_mode) {
  constexpr int BK = 32;
  __shared__ __align__(16) unsigned char sA[128 * 128];
  __shared__ __align__(16) unsigned char sB[128 * 128];

  const int tid = threadIdx.x;
  const int m0 = blockIdx.y << 7;
  const int n0 = blockIdx.x << 7;
  const int wave = tid >> 6, lane = tid & 63;
  const int wr = wave >> 1, wc = wave & 1;
  const int lrow = lane & 15;
  const int lkg = lane >> 4;

  const int r0 = tid >> 3;            // 0..31 -> rows r0+32i
  const int c4 = (tid & 7) << 2;      // k offset 0..28
  const float* xbase = X + (size_t)(m0 + r0) * kC + c4;
  const float* wbase = W + (size_t)(n0 + r0) * kC + c4;
  const int ch = c4 >> 3;             // hi chunk 0..3
  const int slot = (c4 & 7) << 1;     // byte slot 0 or 8

  f32x4 acc[4][4];
#pragma unroll
  for (int a = 0; a < 4; ++a)
#pragma unroll
    for (int b = 0; b < 4; ++b) acc[a][b] = (f32x4){0.f, 0.f, 0.f, 0.f};

  float4 ga[4], gb[4];
#pragma unroll
  for (int i = 0; i < 4; ++i) {
    ga[i] = *reinterpret_cast<const float4*>(xbase + (size_t)i * 32 * kC);
    gb[i] = *reinterpret_cast<const float4*>(wbase + (size_t)i * 32 * kC);
  }

  for (int k0 = 0; k0 < kC; k0 += BK) {
#pragma unroll
    for (int i = 0; i < 4; ++i) {
      const int r = r0 + 32 * i;
      const int rbase = r * 128;
      const int s7 = r & 7;
      ushort4v ha, la, hb2, lb2;
      split4(ga[i], ha, la);
      split4(gb[i], hb2, lb2);
      *reinterpret_cast<ushort4v*>(&sA[rbase + ((ch ^ s7) << 4) + slot]) = ha;
      *reinterpret_cast<ushort4v*>(&sA[rbase + (((ch | 4) ^ s7) << 4) + slot]) = la;
      *reinterpret_cast<ushort4v*>(&sB[rbase + ((ch ^ s7) << 4) + slot]) = hb2;
      *reinterpret_cast<ushort4v*>(&sB[rbase + (((ch | 4) ^ s7) << 4) + slot]) = lb2;
    }
    __syncthreads();

    if (k0 + BK < kC) {
#pragma unroll
      for (int i = 0; i < 4; ++i) {
        ga[i] = *reinterpret_cast<const float4*>(xbase + (k0 + BK) + (size_t)i * 32 * kC);
        gb[i] = *reinterpret_cast<const float4*>(wbase + (k0 + BK) + (size_t)i * 32 * kC);
      }
    }

    short8 ah[4], al[4];
#pragma unroll
    for (int rb = 0; rb < 4; ++rb) {
      const int rA = wr * 64 + rb * 16 + lrow;
      ah[rb] = *reinterpret_cast<const short8*>(&sA[rA * 128 + ((lkg ^ (rA & 7)) << 4)]);
      al[rb] = *reinterpret_cast<const short8*>(&sA[rA * 128 + (((lkg | 4) ^ (rA & 7)) << 4)]);
    }
#pragma unroll
    for (int cb = 0; cb < 4; ++cb) {
      const int rB = wc * 64 + cb * 16 + lrow;
      const short8 bhf = *reinterpret_cast<const short8*>(&sB[rB * 128 + ((lkg ^ (rB & 7)) << 4)]);
      const short8 blf = *reinterpret_cast<const short8*>(&sB[rB * 128 + (((lkg | 4) ^ (rB & 7)) << 4)]);
#pragma unroll
      for (int rb = 0; rb < 4; ++rb) {
        acc[rb][cb] = __builtin_amdgcn_mfma_f32_16x16x32_bf16(ah[rb], bhf, acc[rb][cb], 0, 0, 0);
        acc[rb][cb] = __builtin_amdgcn_mfma_f32_16x16x32_bf16(ah[rb], blf, acc[rb][cb], 0, 0, 0);
        acc[rb][cb] = __builtin_amdgcn_mfma_f32_16x16x32_bf16(al[rb], bhf, acc[rb][cb], 0, 0, 0);
      }
    }
    __syncthreads();
  }

  // Epilogue: bias (+ LoRA), store per out_mode.
#pragma unroll
  for (int rb = 0; rb < 4; ++rb) {
    const int mbase = m0 + wr * 64 + rb * 16 + (lkg << 2);
    float la2[4][kR];
    if (lora_sel >= 0) {
#pragma unroll
      for (int i = 0; i < 4; ++i)
#pragma unroll
        for (int r = 0; r < kR; ++r)
          la2[i][r] = xa[(size_t)(mbase + i) * 16 + lora_sel + r];
    }
#pragma unroll
    for (int cb = 0; cb < 4; ++cb) {
      const int n = n0 + wc * 64 + cb * 16 + lrow;
      const float bi = bias[n];
      float vv[4];
#pragma unroll
      for (int i = 0; i < 4; ++i) {
        vv[i] = acc[rb][cb][i] + bi;
        if (lora_sel >= 0) {
          float lv = 0.f;
#pragma unroll
          for (int r = 0; r < kR; ++r)
            lv = fmaf(la2[i][r], Bm[(size_t)n * kR + r], lv);
          vv[i] += kScaling * lv;
        }
      }
      if (out_mode == 2) {
        // V transposed: [B,H,D,T]; 4 consecutive m = consecutive t.
        const int bb_ = mbase >> 11;
        const int t0 = mbase & (kT - 1);
        const int hh = n >> 6;
        const int dd = n & (kD - 1);
        *reinterpret_cast<float4*>(
            out + (((size_t)bb_ * kH + hh) * kD + dd) * kT + t0) =
            make_float4(vv[0], vv[1], vv[2], vv[3]);
      } else if (out_mode == 1) {
#pragma unroll
        for (int i = 0; i < 4; ++i) {
          const int m = mbase + i;
          const int bb_ = m >> 11;
          const int t = m & (kT - 1);
          const int hh = n >> 6;
          const int dd = n & (kD - 1);
          out[(((size_t)bb_ * kH + hh) * kT + t) * kD + dd] = vv[i];
        }
      } else {
#pragma unroll
        for (int i = 0; i < 4; ++i)
          out[(size_t)(mbase + i) * kC + n] = vv[i];
      }
    }
  }
}

// ---------------------------------------------------------------------------
// Kernel 3: flash attention, bf16 MFMA, QBLK=128, KVBLK=64.
//   4 waves; wave w owns q rows q0+32w .. +31 (2 subtiles of 16).
//   Swapped QK^T (x3): S = mfma(A=K, B=Q); lane holds S[kv=16kvr+4lg+i][q=lrow].
//   P,V bf16; PV: O^T = mfma(A=Vt, B=P).
//   LDS (40 KB): Kh/Kl/Vt 8 KB each + P 16 KB; 128-byte rows, chunk XOR-
//   swizzled by (row&7) -> bank-uniform (T2). K/V global loads for tile t+1
//   are issued before tile t's MFMA phase (T14 reg-prefetch).
// ---------------------------------------------------------------------------
__global__ __launch_bounds__(256) void attn_mfma_kernel(
    const float* __restrict__ q, const float* __restrict__ k,
    const float* __restrict__ vT, float* __restrict__ ctx) {
  __shared__ __align__(16) unsigned char sKh[64 * 128];
  __shared__ __align__(16) unsigned char sKl[64 * 128];
  __shared__ __align__(16) unsigned char sVt[64 * 128];
  __shared__ __align__(16) unsigned char sP[128 * 128];

  const int tid = threadIdx.x;
  const int wave = tid >> 6, lane = tid & 63;
  const int lrow = lane & 15, lg = lane >> 4;
  const int bh = blockIdx.y;
  const int q0 = blockIdx.x << 7;
  const int b = bh >> 4, h = bh & 15;

  const float* qbh = q + (size_t)bh * kT * kD;
  const float* kbh = k + (size_t)bh * kT * kD;

  // Staging coords: srow = K row (t-local) / V row (d); scq = 16-float col.
  const int srow = tid >> 2;
  const int scq = (tid & 3) << 4;
  const float* kstage = kbh + (size_t)srow * kD + scq;
  const float* vstage = vT + ((size_t)bh * kD + srow) * kT + scq;

  // ---- Q fragments direct from global (scaled 1/8, hi/lo split).
  short8 qh[2][2], ql[2][2];
#pragma unroll
  for (int qs = 0; qs < 2; ++qs)
#pragma unroll
    for (int d0 = 0; d0 < 2; ++d0) {
      const int qrow = q0 + wave * 32 + qs * 16 + lrow;
      const float* qp2 = qbh + (size_t)qrow * kD + d0 * 32 + lg * 8;
      float4 f0 = *reinterpret_cast<const float4*>(qp2);
      float4 f1 = *reinterpret_cast<const float4*>(qp2 + 4);
      f0.x *= kInvSqrtD; f0.y *= kInvSqrtD; f0.z *= kInvSqrtD; f0.w *= kInvSqrtD;
      f1.x *= kInvSqrtD; f1.y *= kInvSqrtD; f1.z *= kInvSqrtD; f1.w *= kInvSqrtD;
      ushort4v h0, l0, h1, l1;
      split4(f0, h0, l0);
      split4(f1, h1, l1);
      qh[qs][d0] = pack8(h0, h1);
      ql[qs][d0] = pack8(l0, l1);
    }

  f32x4 acc_o[2][4];
#pragma unroll
  for (int qs = 0; qs < 2; ++qs)
#pragma unroll
    for (int dr = 0; dr < 4; ++dr) acc_o[qs][dr] = (f32x4){0.f, 0.f, 0.f, 0.f};
  float m_i[2] = {-3.0e38f, -3.0e38f};
  float l_i[2] = {0.f, 0.f};

  constexpr int kNT = kT / 64;
  float4 kpre[4], vpre[4];
#pragma unroll
  for (int i = 0; i < 4; ++i) {
    kpre[i] = *reinterpret_cast<const float4*>(kstage + i * 4);
    vpre[i] = *reinterpret_cast<const float4*>(vstage + i * 4);
  }

  for (int kt = 0; kt < kNT; ++kt) {
    // ---- Write prefetched tile into LDS (split K hi/lo, cvt V to bf16).
    {
      const int s7k = srow & 7;
#pragma unroll
      for (int half = 0; half < 2; ++half) {
        ushort4v h0, l0, h1, l1;
        split4(kpre[2 * half], h0, l0);
        split4(kpre[2 * half + 1], h1, l1);
        const int chk = ((scq >> 3) + half) ^ s7k;
        *reinterpret_cast<ushort8v*>(&sKh[srow * 128 + (chk << 4)]) =
            (ushort8v){h0[0], h0[1], h0[2], h0[3], h1[0], h1[1], h1[2], h1[3]};
        *reinterpret_cast<ushort8v*>(&sKl[srow * 128 + (chk << 4)]) =
            (ushort8v){l0[0], l0[1], l0[2], l0[3], l1[0], l1[1], l1[2], l1[3]};
        ushort8v w;
        const float vf0[8] = {vpre[2 * half].x, vpre[2 * half].y,
                              vpre[2 * half].z, vpre[2 * half].w,
                              vpre[2 * half + 1].x, vpre[2 * half + 1].y,
                              vpre[2 * half + 1].z, vpre[2 * half + 1].w};
#pragma unroll
        for (int e = 0; e < 8; ++e) w[e] = (unsigned short)f32_to_bf16_rne(vf0[e]);
        *reinterpret_cast<ushort8v*>(&sVt[srow * 128 + (chk << 4)]) = w;
      }
    }
    __syncthreads();

    // ---- Issue global loads for tile kt+1 (hidden under MFMA below).
    if (kt + 1 < kNT) {
      const int knext = (kt + 1) << 6;
#pragma unroll
      for (int i = 0; i < 4; ++i) {
        kpre[i] = *reinterpret_cast<const float4*>(kstage + (size_t)knext * kD + i * 4);
        vpre[i] = *reinterpret_cast<const float4*>(vstage + knext + i * 4);
      }
    }

    // ---- S = K·Q^T (x3): acc_s[qs][kvr], lane = S[kv=16kvr+4lg+i][q=lrow].
    f32x4 acc_s[2][4];
#pragma unroll
    for (int qs = 0; qs < 2; ++qs)
#pragma unroll
      for (int kvr = 0; kvr < 4; ++kvr) acc_s[qs][kvr] = (f32x4){0.f, 0.f, 0.f, 0.f};
#pragma unroll
    for (int d0 = 0; d0 < 2; ++d0) {
#pragma unroll
      for (int kvr = 0; kvr < 4; ++kvr) {
        const int rk = kvr * 16 + lrow;
        const int byt = rk * 128 + ((((d0 << 2) + lg) ^ (rk & 7)) << 4);
        const short8 khf = *reinterpret_cast<const short8*>(&sKh[byt]);
        const short8 klf = *reinterpret_cast<const short8*>(&sKl[byt]);
#pragma unroll
        for (int qs = 0; qs < 2; ++qs) {
          acc_s[qs][kvr] = __builtin_amdgcn_mfma_f32_16x16x32_bf16(khf, qh[qs][d0], acc_s[qs][kvr], 0, 0, 0);
          acc_s[qs][kvr] = __builtin_amdgcn_mfma_f32_16x16x32_bf16(khf, ql[qs][d0], acc_s[qs][kvr], 0, 0, 0);
          acc_s[qs][kvr] = __builtin_amdgcn_mfma_f32_16x16x32_bf16(klf, qh[qs][d0], acc_s[qs][kvr], 0, 0, 0);
        }
      }
    }

    // ---- Online softmax per q-subtile (reduce over lg groups: xor 16,32).
#pragma unroll
    for (int qs = 0; qs < 2; ++qs) {
      float mx = acc_s[qs][0][0];
#pragma unroll
      for (int kvr = 0; kvr < 4; ++kvr)
#pragma unroll
        for (int i = 0; i < 4; ++i) mx = fmaxf(mx, acc_s[qs][kvr][i]);
      mx = fmaxf(mx, __shfl_xor(mx, 16, 64));
      mx = fmaxf(mx, __shfl_xor(mx, 32, 64));
      const float mnew = fmaxf(m_i[qs], mx);
      const float alpha = __expf(m_i[qs] - mnew);
      m_i[qs] = mnew;
      const int prow = wave * 32 + qs * 16 + lrow;
      const int p7 = prow & 7;
      float rs = 0.f;
#pragma unroll
      for (int kvr = 0; kvr < 4; ++kvr) {
        ushort4v pu;
#pragma unroll
        for (int i = 0; i < 4; ++i) {
          const float pv = __expf(acc_s[qs][kvr][i] - mnew);
          rs += pv;
          pu[i] = (unsigned short)f32_to_bf16_rne(pv);
        }
        const int chunk = ((kvr << 1) + (lg >> 1)) ^ p7;
        *reinterpret_cast<ushort4v*>(&sP[prow * 128 + (chunk << 4) + ((lg & 1) << 3)]) = pu;
      }
      rs += __shfl_xor(rs, 16, 64);
      rs += __shfl_xor(rs, 32, 64);
      l_i[qs] = l_i[qs] * alpha + rs;
#pragma unroll
      for (int dr = 0; dr < 4; ++dr)
#pragma unroll
        for (int i = 0; i < 4; ++i) acc_o[qs][dr][i] *= alpha;
    }
    __builtin_amdgcn_sched_barrier(0);  // P writes precede P reads (same wave)

    // ---- O^T += Vt·P^T.
#pragma unroll
    for (int ks = 0; ks < 2; ++ks) {
      short8 pf[2];
#pragma unroll
      for (int qs = 0; qs < 2; ++qs) {
        const int prow = wave * 32 + qs * 16 + lrow;
        pf[qs] = *reinterpret_cast<const short8*>(
            &sP[prow * 128 + ((((ks << 2) + lg) ^ (prow & 7)) << 4)]);
      }
#pragma unroll
      for (int dr = 0; dr < 4; ++dr) {
        const int rv = dr * 16 + lrow;
        const short8 vf = *reinterpret_cast<const short8*>(
            &sVt[rv * 128 + ((((ks << 2) + lg) ^ (rv & 7)) << 4)]);
        acc_o[0][dr] = __builtin_amdgcn_mfma_f32_16x16x32_bf16(vf, pf[0], acc_o[0][dr], 0, 0, 0);
        acc_o[1][dr] = __builtin_amdgcn_mfma_f32_16x16x32_bf16(vf, pf[1], acc_o[1][dr], 0, 0, 0);
      }
    }
    __syncthreads();
  }

  // ---- Epilogue: O[q][d] = acc_o/l -> ctx [B,T,C], C = h*64 + d.
#pragma unroll
  for (int qs = 0; qs < 2; ++qs) {
    const float inv = 1.0f / l_i[qs];
    const int qq = q0 + wave * 32 + qs * 16 + lrow;
    float* op = ctx + ((size_t)b * kT + qq) * kC + (h << 6);
#pragma unroll
    for (int dr = 0; dr < 4; ++dr) {
      const float4 o4 = make_float4(acc_o[qs][dr][0] * inv, acc_o[qs][dr][1] * inv,
                                    acc_o[qs][dr][2] * inv, acc_o[qs][dr][3] * inv);
      *reinterpret_cast<float4*>(op + dr * 16 + (lg << 2)) = o4;
    }
  }
}

// ---------------------------------------------------------------------------
extern "C" void kernel_launch(void* const* d_in, const int* in_sizes, int n_in,
                              void* d_out, int out_size, void* d_ws, size_t ws_size,
                              hipStream_t stream) {
  const float* x  = (const float*)d_in[0];
  const float* Wq = (const float*)d_in[1];
  const float* bq = (const float*)d_in[2];
  const float* Wk = (const float*)d_in[3];
  const float* bk = (const float*)d_in[4];
  const float* Wv = (const float*)d_in[5];
  const float* bv = (const float*)d_in[6];
  const float* Wo = (const float*)d_in[7];
  const float* bo = (const float*)d_in[8];
  const float* Aq = (const float*)d_in[9];
  const float* Bq = (const float*)d_in[10];
  const float* Av = (const float*)d_in[11];
  const float* Bv = (const float*)d_in[12];
  float* out = (float*)d_out;

  float* ws = (float*)d_ws;
  float* qb  = ws;                              // [B,H,T,D]
  float* kb  = qb  + (size_t)kM * kC;           // [B,H,T,D]
  float* vbT = kb  + (size_t)kM * kC;           // [B,H,D,T]
  float* ctx = vbT + (size_t)kM * kC;           // [B,T,C]
  float* xa  = ctx + (size_t)kM * kC;           // [M,16]

  hipLaunchKernelGGL(lora_xa_kernel, dim3(kM / 4), dim3(256), 0, stream,
                     x, Aq, Av, xa);

  const dim3 gg(kC / 128, kM / 128);
  hipLaunchKernelGGL(gemm_bf16x3_kernel, gg, dim3(256), 0, stream,
                     x, Wq, bq, xa, Bq, qb, 0, 1);
  hipLaunchKernelGGL(gemm_bf16x3_kernel, gg, dim3(256), 0, stream,
                     x, Wk, bk, nullptr, nullptr, kb, -1, 1);
  hipLaunchKernelGGL(gemm_bf16x3_kernel, gg, dim3(256), 0, stream,
                     x, Wv, bv, xa, Bv, vbT, 8, 2);

  hipLaunchKernelGGL(attn_mfma_kernel, dim3(kT / 128, kB * kH), dim3(256), 0, stream,
                     qb, kb, vbT, ctx);

  hipLaunchKernelGGL(gemm_bf16x3_kernel, gg, dim3(256), 0, stream,
                     ctx, Wo, bo, nullptr, nullptr, out, -1, 0);
}